// Round 1
// baseline (724.427 us; speedup 1.0000x reference)
//
#include <hip/hip_runtime.h>

// Problem constants (fixed by the reference)
constexpr int BB = 32;     // batch
constexpr int DD = 384;    // latent dim
constexpr int TN = 4096;   // sequence length
constexpr int KK = 256;    // codebook size
constexpr float BETA = 0.25f;

constexpr int TT  = 32;           // tokens per block
constexpr int DG  = DD / 4;       // 96 float4 groups along D
constexpr int ECH = 2;            // dg-groups per codebook LDS chunk
constexpr int NCH = DG / ECH;     // 48 chunks

constexpr size_t QSIZE = (size_t)BB * DD * TN;   // 50331648
constexpr size_t ISIZE = (size_t)BB * TN;        // 131072

// --- tiny pre-pass: per-code squared norms into workspace ---
__global__ void e2_kernel(const float* __restrict__ cb, float* __restrict__ e2) {
    int c = threadIdx.x;             // 256 threads == KK
    const float4* row = (const float4*)(cb + (size_t)c * DD);
    float s = 0.f;
    #pragma unroll
    for (int g = 0; g < DG; ++g) {
        float4 v = row[g];
        s += v.x * v.x + v.y * v.y + v.z * v.z + v.w * v.w;
    }
    e2[c] = s;
}

// --- main fused kernel: distances + argmin + quantize + indices + loss ---
__global__ __launch_bounds__(256, 2)
void vq_kernel(const float* __restrict__ z, const float* __restrict__ cb,
               const float* __restrict__ e2g, float* __restrict__ out) {
    __shared__ float4 xs4[DG][TT];     // 48 KB  z tile, [d-group][token]
    __shared__ float4 es4[ECH][KK];    //  8 KB  codebook chunk, [dgl][code]
    __shared__ float  e2s[KK];         //  1 KB
    __shared__ int    idxs[TT];
    __shared__ float  wsum[4];

    const int tid = threadIdx.x;
    const int bid = blockIdx.x;
    const int b   = bid >> 7;                 // TN/TT = 128 tiles per batch
    const int t0  = (bid & 127) * TT;

    const int tx = tid & 31;                  // -> codes c = tx + 32*j
    const int ty = tid >> 5;                  // -> tokens t = ty*4 + i

    // stage per-code norms
    e2s[tid] = e2g[tid];

    // stage z tile: xs4[dg][tt] = z[b][4dg..4dg+3][t0+tt]
    {
        const float* zb = z + (size_t)b * DD * TN + t0;
        const int tt = tid & 31;
        const int g  = tid >> 5;
        #pragma unroll
        for (int m = 0; m < 12; ++m) {
            int dg = g + 8 * m;
            float4 v;
            v.x = zb[(size_t)(4 * dg + 0) * TN + tt];
            v.y = zb[(size_t)(4 * dg + 1) * TN + tt];
            v.z = zb[(size_t)(4 * dg + 2) * TN + tt];
            v.w = zb[(size_t)(4 * dg + 3) * TN + tt];
            xs4[dg][tt] = v;
        }
    }

    float acc[4][8];
    #pragma unroll
    for (int i = 0; i < 4; ++i)
        #pragma unroll
        for (int j = 0; j < 8; ++j) acc[i][j] = 0.f;

    const float4* cb4 = (const float4*)cb;

    for (int ch = 0; ch < NCH; ++ch) {
        const int dgb = ch * ECH;
        __syncthreads();   // protect es4 from previous iteration's readers
                           // (first pass: also fences xs4 staging)
        // stage codebook chunk: es4[dgl][c] = cb[c][4(dgb+dgl) .. +3]
        {
            const int c = tid;
            #pragma unroll
            for (int dgl = 0; dgl < ECH; ++dgl)
                es4[dgl][c] = cb4[(size_t)c * DG + dgb + dgl];
        }
        __syncthreads();

        #pragma unroll
        for (int dgl = 0; dgl < ECH; ++dgl) {
            const int dg = dgb + dgl;
            float4 xv[4];
            #pragma unroll
            for (int i = 0; i < 4; ++i) xv[i] = xs4[dg][ty * 4 + i];  // broadcast
            #pragma unroll
            for (int j = 0; j < 8; ++j) {
                float4 ev = es4[dgl][tx + 32 * j];                    // contiguous b128
                #pragma unroll
                for (int i = 0; i < 4; ++i) {
                    acc[i][j] += xv[i].x * ev.x;
                    acc[i][j] += xv[i].y * ev.y;
                    acc[i][j] += xv[i].z * ev.z;
                    acc[i][j] += xv[i].w * ev.w;
                }
            }
        }
    }

    // per-thread argmin over its 8 codes (c ascending => first-min kept)
    float bv[4]; int bi[4];
    #pragma unroll
    for (int i = 0; i < 4; ++i) { bv[i] = 3.4e38f; bi[i] = 0x7fffffff; }
    #pragma unroll
    for (int j = 0; j < 8; ++j) {
        const int c = tx + 32 * j;
        const float e2c = e2s[c];
        #pragma unroll
        for (int i = 0; i < 4; ++i) {
            float v = e2c - 2.f * acc[i][j];    // x^2 is constant per token: drop it
            if (v < bv[i]) { bv[i] = v; bi[i] = c; }
        }
    }
    // cross-lane reduce over the 32 tx lanes (lexicographic: val, then index)
    #pragma unroll
    for (int m = 16; m >= 1; m >>= 1) {
        #pragma unroll
        for (int i = 0; i < 4; ++i) {
            float ov = __shfl_xor(bv[i], m, 64);
            int   oi = __shfl_xor(bi[i], m, 64);
            if (ov < bv[i] || (ov == bv[i] && oi < bi[i])) { bv[i] = ov; bi[i] = oi; }
        }
    }
    if (tx == 0) {
        #pragma unroll
        for (int i = 0; i < 4; ++i) idxs[ty * 4 + i] = bi[i];
    }
    __syncthreads();

    // epilogue: quantize output (coalesced over t), loss partials
    {
        const int tt = tid & 31;
        const int g  = tid >> 5;
        const int myi = idxs[tt];
        const float4* crow = cb4 + (size_t)myi * DG;
        float* outq = out + (size_t)b * DD * TN + t0;
        float lsum = 0.f;
        #pragma unroll
        for (int m = 0; m < 12; ++m) {
            int dg = g + 8 * m;
            float4 q = crow[dg];       // L1/L2-hot gather
            float4 x = xs4[dg][tt];    // still resident in LDS
            float dx = q.x - x.x, dy = q.y - x.y, dz = q.z - x.z, dw = q.w - x.w;
            lsum += dx * dx + dy * dy + dz * dz + dw * dw;
            outq[(size_t)(4 * dg + 0) * TN + tt] = q.x;
            outq[(size_t)(4 * dg + 1) * TN + tt] = q.y;
            outq[(size_t)(4 * dg + 2) * TN + tt] = q.z;
            outq[(size_t)(4 * dg + 3) * TN + tt] = q.w;
        }
        // indices output (as float: whole out buffer is fp32)
        if (tid < TT)
            out[QSIZE + (size_t)b * TN + t0 + tid] = (float)idxs[tid];

        // loss: wave reduce -> block reduce -> one atomic
        #pragma unroll
        for (int m = 32; m >= 1; m >>= 1) lsum += __shfl_xor(lsum, m, 64);
        if ((tid & 63) == 0) wsum[tid >> 6] = lsum;
        __syncthreads();
        if (tid == 0) {
            float s = wsum[0] + wsum[1] + wsum[2] + wsum[3];
            atomicAdd(out + QSIZE + ISIZE,
                      s * (BETA / (float)((size_t)BB * DD * TN)));
        }
    }
}

extern "C" void kernel_launch(void* const* d_in, const int* in_sizes, int n_in,
                              void* d_out, int out_size, void* d_ws, size_t ws_size,
                              hipStream_t stream) {
    (void)in_sizes; (void)n_in; (void)out_size; (void)ws_size;
    const float* z  = (const float*)d_in[0];
    const float* cb = (const float*)d_in[1];
    float* out  = (float*)d_out;
    float* e2ws = (float*)d_ws;

    // d_out is poisoned 0xAA before every timed launch: zero the loss slot
    hipMemsetAsync(out + QSIZE + ISIZE, 0, sizeof(float), stream);
    e2_kernel<<<dim3(1), dim3(256), 0, stream>>>(cb, e2ws);
    vq_kernel<<<dim3(BB * (TN / TT)), dim3(256), 0, stream>>>(z, cb, e2ws, out);
}